// Round 1
// baseline (1060.138 us; speedup 1.0000x reference)
//
#include <hip/hip_runtime.h>
#include <math.h>

#define N_NODES 100000
#define N_EDGES 1250000
#define IN_DIM 6
#define HID 64

// --- degree histogram: counts[dst]++ ---------------------------------------
__global__ void degree_hist(const int* __restrict__ dst, int* __restrict__ counts) {
    int e = blockIdx.x * blockDim.x + threadIdx.x;
    if (e < N_EDGES) atomicAdd(&counts[dst[e]], 1);
}

// --- single-block exclusive scan over counts -> row_ptr, cursor, dis -------
__global__ __launch_bounds__(1024) void scan_kernel(const int* __restrict__ counts,
                                                    int* __restrict__ row_ptr,
                                                    int* __restrict__ cursor,
                                                    float* __restrict__ dis) {
    __shared__ int sums[1024];
    int t = threadIdx.x;
    const int chunk = (N_NODES + 1023) / 1024;  // 98
    int lo = t * chunk;
    int hi = min(lo + chunk, N_NODES);
    int s = 0;
    for (int i = lo; i < hi; ++i) s += counts[i];
    sums[t] = s;
    __syncthreads();
    for (int off = 1; off < 1024; off <<= 1) {
        int add = (t >= off) ? sums[t - off] : 0;
        __syncthreads();
        sums[t] += add;
        __syncthreads();
    }
    int run = (t == 0) ? 0 : sums[t - 1];
    for (int i = lo; i < hi; ++i) {
        row_ptr[i] = run;
        cursor[i]  = run;
        int c = counts[i];
        dis[i] = rsqrtf((float)c + 1.0f);  // deg includes self-loop
        run += c;
    }
    if (t == 1023) row_ptr[N_NODES] = sums[1023];
}

// --- bucket fill: CSR-by-dst edge list (order within bucket irrelevant) ----
__global__ void bucket_kernel(const int* __restrict__ src, const int* __restrict__ dst,
                              int* __restrict__ cursor, int* __restrict__ srcsorted) {
    int e = blockIdx.x * blockDim.x + threadIdx.x;
    if (e < N_EDGES) {
        int d = dst[e];
        int pos = atomicAdd(&cursor[d], 1);
        srcsorted[pos] = src[e];
    }
}

// --- p1 = (x @ W1) * dis[n]  (6 -> 64) -------------------------------------
__global__ void gemm1_kernel(const float* __restrict__ x, const float* __restrict__ W1,
                             const float* __restrict__ dis, float* __restrict__ p1) {
    __shared__ float w[IN_DIM * HID];
    int tid = threadIdx.x;
    for (int i = tid; i < IN_DIM * HID; i += blockDim.x) w[i] = W1[i];
    __syncthreads();
    int g = blockIdx.x * blockDim.x + tid;
    int n = g >> 6, c = g & 63;
    if (n >= N_NODES) return;
    float sum = 0.f;
#pragma unroll
    for (int k = 0; k < IN_DIM; ++k) sum += x[n * IN_DIM + k] * w[k * HID + c];
    p1[n * HID + c] = sum * dis[n];
}

// --- out1 = relu(dis[n]*(p1[n] + sum_in p1[src]) + b1) ---------------------
__global__ void agg1_kernel(const float* __restrict__ p1, const int* __restrict__ row_ptr,
                            const int* __restrict__ srcsorted, const float* __restrict__ dis,
                            const float* __restrict__ b1, float* __restrict__ out1) {
    int g = blockIdx.x * blockDim.x + threadIdx.x;
    int n = g >> 6, c = g & 63;  // one wave per node, lane = channel
    if (n >= N_NODES) return;
    float acc = p1[n * HID + c];
    int beg = row_ptr[n], end = row_ptr[n + 1];
    for (int j = beg; j < end; ++j) {
        int s = srcsorted[j];
        acc += p1[s * HID + c];
    }
    float v = dis[n] * acc + b1[c];
    out1[n * HID + c] = fmaxf(v, 0.f);
}

// --- p2 = (out1 @ W2) * dis[n]  (64 -> 64) ---------------------------------
__global__ void gemm2_kernel(const float* __restrict__ h, const float* __restrict__ W2,
                             const float* __restrict__ dis, float* __restrict__ p2) {
    __shared__ float w[HID * HID];
    int tid = threadIdx.x;
    for (int i = tid; i < HID * HID; i += blockDim.x) w[i] = W2[i];
    __syncthreads();
    int g = blockIdx.x * blockDim.x + tid;
    int n = g >> 6, c = g & 63;
    if (n >= N_NODES) return;
    const float* hr = h + n * HID;
    float sum = 0.f;
#pragma unroll
    for (int k = 0; k < HID; ++k) sum += hr[k] * w[k * HID + c];
    p2[n * HID + c] = sum * dis[n];
}

// --- layer-2 aggregation fused with column-sum readout ---------------------
__global__ void agg2_kernel(const float* __restrict__ p2, const int* __restrict__ row_ptr,
                            const int* __restrict__ srcsorted, const float* __restrict__ dis,
                            const float* __restrict__ b2, float* __restrict__ gsum) {
    __shared__ float red[256];
    int tid = threadIdx.x;
    int lane = tid & 63;
    int wv = (blockIdx.x * blockDim.x + tid) >> 6;
    int nwaves = (gridDim.x * blockDim.x) >> 6;
    float sum = 0.f;
    for (int n = wv; n < N_NODES; n += nwaves) {
        float acc = p2[n * HID + lane];
        int beg = row_ptr[n], end = row_ptr[n + 1];
        for (int j = beg; j < end; ++j) acc += p2[srcsorted[j] * HID + lane];
        sum += dis[n] * acc + b2[lane];  // no relu on layer 2
    }
    red[tid] = sum;
    __syncthreads();
    if (tid < 64) {
        float t = red[tid] + red[tid + 64] + red[tid + 128] + red[tid + 192];
        atomicAdd(&gsum[tid], t);
    }
}

// --- final: sigmoid(mean(h2) @ Wfc + bfc) ----------------------------------
__global__ void final_kernel(const float* __restrict__ gsum, const float* __restrict__ Wfc,
                             const float* __restrict__ bfc, float* __restrict__ out) {
    int t = threadIdx.x;
    float v = gsum[t] * (1.0f / N_NODES) * Wfc[t];
    for (int off = 32; off > 0; off >>= 1) v += __shfl_down(v, off, 64);
    if (t == 0) out[0] = 1.0f / (1.0f + expf(-(v + bfc[0])));
}

extern "C" void kernel_launch(void* const* d_in, const int* in_sizes, int n_in,
                              void* d_out, int out_size, void* d_ws, size_t ws_size,
                              hipStream_t stream) {
    const float* x   = (const float*)d_in[0];
    const int*   ei  = (const int*)d_in[1];   // (2, E) row-major int32
    const float* W1  = (const float*)d_in[2];
    const float* b1  = (const float*)d_in[3];
    const float* W2  = (const float*)d_in[4];
    const float* b2  = (const float*)d_in[5];
    const float* Wfc = (const float*)d_in[6];
    const float* bfc = (const float*)d_in[7];
    const int* src = ei;
    const int* dst = ei + N_EDGES;

    char* ws = (char*)d_ws;
    size_t off = 0;
    auto alloc = [&](size_t bytes) {
        char* p = ws + off;
        off += (bytes + 255) & ~(size_t)255;
        return p;
    };
    float* bufA      = (float*)alloc((size_t)N_NODES * HID * 4);  // p1, then p2
    float* bufB      = (float*)alloc((size_t)N_NODES * HID * 4);  // out1
    float* dis       = (float*)alloc((size_t)N_NODES * 4);
    int*   counts    = (int*)  alloc((size_t)N_NODES * 4);
    int*   row_ptr   = (int*)  alloc((size_t)(N_NODES + 1) * 4);
    int*   cursor    = (int*)  alloc((size_t)N_NODES * 4);
    int*   srcsorted = (int*)  alloc((size_t)N_EDGES * 4);
    float* gsum      = (float*)alloc(64 * 4);

    hipMemsetAsync(counts, 0, (size_t)N_NODES * 4, stream);
    hipMemsetAsync(gsum, 0, 64 * 4, stream);

    int eb = (N_EDGES + 255) / 256;
    int nb = (N_NODES * HID + 255) / 256;

    degree_hist<<<eb, 256, 0, stream>>>(dst, counts);
    scan_kernel<<<1, 1024, 0, stream>>>(counts, row_ptr, cursor, dis);
    bucket_kernel<<<eb, 256, 0, stream>>>(src, dst, cursor, srcsorted);
    gemm1_kernel<<<nb, 256, 0, stream>>>(x, W1, dis, bufA);
    agg1_kernel<<<nb, 256, 0, stream>>>(bufA, row_ptr, srcsorted, dis, b1, bufB);
    gemm2_kernel<<<nb, 256, 0, stream>>>(bufB, W2, dis, bufA);
    agg2_kernel<<<512, 256, 0, stream>>>(bufA, row_ptr, srcsorted, dis, b2, gsum);
    final_kernel<<<1, 64, 0, stream>>>(gsum, Wfc, bfc, (float*)d_out);
}

// Round 2
// 742.104 us; speedup vs baseline: 1.4286x; 1.4286x over previous
//
#include <hip/hip_runtime.h>
#include <math.h>

#define N_NODES 100000
#define N_EDGES 1250000
#define IN_DIM 6
#define HID 64

// --- degree histogram: counts[dst]++ ---------------------------------------
__global__ void degree_hist(const int* __restrict__ dst, int* __restrict__ counts) {
    int e = blockIdx.x * blockDim.x + threadIdx.x;
    if (e < N_EDGES) atomicAdd(&counts[dst[e]], 1);
}

// --- single-block exclusive scan over counts -> row_ptr, cursor, dis -------
__global__ __launch_bounds__(1024) void scan_kernel(const int* __restrict__ counts,
                                                    int* __restrict__ row_ptr,
                                                    int* __restrict__ cursor,
                                                    float* __restrict__ dis) {
    __shared__ int sums[1024];
    int t = threadIdx.x;
    const int chunk = (N_NODES + 1023) / 1024;  // 98
    int lo = t * chunk;
    int hi = min(lo + chunk, N_NODES);
    int s = 0;
    for (int i = lo; i < hi; ++i) s += counts[i];
    sums[t] = s;
    __syncthreads();
    for (int off = 1; off < 1024; off <<= 1) {
        int add = (t >= off) ? sums[t - off] : 0;
        __syncthreads();
        sums[t] += add;
        __syncthreads();
    }
    int run = (t == 0) ? 0 : sums[t - 1];
    for (int i = lo; i < hi; ++i) {
        row_ptr[i] = run;
        cursor[i]  = run;
        int c = counts[i];
        dis[i] = rsqrtf((float)c + 1.0f);  // deg includes self-loop
        run += c;
    }
    if (t == 1023) row_ptr[N_NODES] = sums[1023];
}

// --- bucket fill: CSR-by-dst edge list (order within bucket irrelevant) ----
__global__ void bucket_kernel(const int* __restrict__ src, const int* __restrict__ dst,
                              int* __restrict__ cursor, int* __restrict__ srcsorted) {
    int e = blockIdx.x * blockDim.x + threadIdx.x;
    if (e < N_EDGES) {
        int d = dst[e];
        int pos = atomicAdd(&cursor[d], 1);
        srcsorted[pos] = src[e];
    }
}

// --- p1 = (x @ W1) * dis[n]  (6 -> 64) -------------------------------------
__global__ void gemm1_kernel(const float* __restrict__ x, const float* __restrict__ W1,
                             const float* __restrict__ dis, float* __restrict__ p1) {
    __shared__ float w[IN_DIM * HID];
    int tid = threadIdx.x;
    for (int i = tid; i < IN_DIM * HID; i += blockDim.x) w[i] = W1[i];
    __syncthreads();
    int g = blockIdx.x * blockDim.x + tid;
    int n = g >> 6, c = g & 63;
    if (n >= N_NODES) return;
    float sum = 0.f;
#pragma unroll
    for (int k = 0; k < IN_DIM; ++k) sum += x[n * IN_DIM + k] * w[k * HID + c];
    p1[n * HID + c] = sum * dis[n];
}

// --- generic aggregation: out[n] = act(dis[n]*(p[n] + sum_in p[src]) + b) --
// One wave per node, lane = channel. Edge loop unrolled x4: 4 independent
// index loads then 4 independent row loads per iteration (4x MLP vs serial).
template <bool RELU>
__global__ void agg_kernel(const float* __restrict__ p, const int* __restrict__ row_ptr,
                           const int* __restrict__ srcsorted, const float* __restrict__ dis,
                           const float* __restrict__ b, float* __restrict__ out) {
    int g = blockIdx.x * blockDim.x + threadIdx.x;
    int n = g >> 6, c = g & 63;
    if (n >= N_NODES) return;
    int beg = row_ptr[n], end = row_ptr[n + 1];
    float a0 = p[n * HID + c], a1 = 0.f, a2 = 0.f, a3 = 0.f;
    int j = beg;
    for (; j + 4 <= end; j += 4) {
        int s0 = srcsorted[j];
        int s1 = srcsorted[j + 1];
        int s2 = srcsorted[j + 2];
        int s3 = srcsorted[j + 3];
        a0 += p[s0 * HID + c];
        a1 += p[s1 * HID + c];
        a2 += p[s2 * HID + c];
        a3 += p[s3 * HID + c];
    }
    for (; j < end; ++j) a0 += p[srcsorted[j] * HID + c];
    float acc = (a0 + a1) + (a2 + a3);
    float v = dis[n] * acc + b[c];
    out[n * HID + c] = RELU ? fmaxf(v, 0.f) : v;
}

// --- p2 = (out1 @ W2) * dis[n]  (64 -> 64) ---------------------------------
__global__ void gemm2_kernel(const float* __restrict__ h, const float* __restrict__ W2,
                             const float* __restrict__ dis, float* __restrict__ p2) {
    __shared__ float w[HID * HID];
    int tid = threadIdx.x;
    for (int i = tid; i < HID * HID; i += blockDim.x) w[i] = W2[i];
    __syncthreads();
    int g = blockIdx.x * blockDim.x + tid;
    int n = g >> 6, c = g & 63;
    if (n >= N_NODES) return;
    const float* hr = h + n * HID;
    float sum = 0.f;
#pragma unroll
    for (int k = 0; k < HID; ++k) sum += hr[k] * w[k * HID + c];
    p2[n * HID + c] = sum * dis[n];
}

// --- column sum of h2 [N, 64] -> gsum[64] ----------------------------------
__global__ void colsum_kernel(const float* __restrict__ h2, float* __restrict__ gsum) {
    __shared__ float red[256];
    int tid = threadIdx.x;
    int lane = tid & 63;
    int w = tid >> 6;  // 4 waves per block
    float sum = 0.f;
    for (int n = blockIdx.x * 4 + w; n < N_NODES; n += gridDim.x * 4)
        sum += h2[n * HID + lane];
    red[tid] = sum;
    __syncthreads();
    if (tid < 64)
        atomicAdd(&gsum[tid], red[tid] + red[tid + 64] + red[tid + 128] + red[tid + 192]);
}

// --- final: sigmoid(mean(h2) @ Wfc + bfc) ----------------------------------
__global__ void final_kernel(const float* __restrict__ gsum, const float* __restrict__ Wfc,
                             const float* __restrict__ bfc, float* __restrict__ out) {
    int t = threadIdx.x;
    float v = gsum[t] * (1.0f / N_NODES) * Wfc[t];
    for (int off = 32; off > 0; off >>= 1) v += __shfl_down(v, off, 64);
    if (t == 0) out[0] = 1.0f / (1.0f + expf(-(v + bfc[0])));
}

extern "C" void kernel_launch(void* const* d_in, const int* in_sizes, int n_in,
                              void* d_out, int out_size, void* d_ws, size_t ws_size,
                              hipStream_t stream) {
    const float* x   = (const float*)d_in[0];
    const int*   ei  = (const int*)d_in[1];   // (2, E) row-major int32
    const float* W1  = (const float*)d_in[2];
    const float* b1  = (const float*)d_in[3];
    const float* W2  = (const float*)d_in[4];
    const float* b2  = (const float*)d_in[5];
    const float* Wfc = (const float*)d_in[6];
    const float* bfc = (const float*)d_in[7];
    const int* src = ei;
    const int* dst = ei + N_EDGES;

    char* ws = (char*)d_ws;
    size_t off = 0;
    auto alloc = [&](size_t bytes) {
        char* p = ws + off;
        off += (bytes + 255) & ~(size_t)255;
        return p;
    };
    float* bufA      = (float*)alloc((size_t)N_NODES * HID * 4);  // p1, then p2
    float* bufB      = (float*)alloc((size_t)N_NODES * HID * 4);  // out1, then h2
    float* dis       = (float*)alloc((size_t)N_NODES * 4);
    int*   counts    = (int*)  alloc((size_t)N_NODES * 4);
    int*   row_ptr   = (int*)  alloc((size_t)(N_NODES + 1) * 4);
    int*   cursor    = (int*)  alloc((size_t)N_NODES * 4);
    int*   srcsorted = (int*)  alloc((size_t)N_EDGES * 4);
    float* gsum      = (float*)alloc(64 * 4);

    hipMemsetAsync(counts, 0, (size_t)N_NODES * 4, stream);
    hipMemsetAsync(gsum, 0, 64 * 4, stream);

    int eb = (N_EDGES + 255) / 256;
    int nb = (N_NODES * HID + 255) / 256;

    degree_hist<<<eb, 256, 0, stream>>>(dst, counts);
    scan_kernel<<<1, 1024, 0, stream>>>(counts, row_ptr, cursor, dis);
    bucket_kernel<<<eb, 256, 0, stream>>>(src, dst, cursor, srcsorted);
    gemm1_kernel<<<nb, 256, 0, stream>>>(x, W1, dis, bufA);
    agg_kernel<true><<<nb, 256, 0, stream>>>(bufA, row_ptr, srcsorted, dis, b1, bufB);
    gemm2_kernel<<<nb, 256, 0, stream>>>(bufB, W2, dis, bufA);
    agg_kernel<false><<<nb, 256, 0, stream>>>(bufA, row_ptr, srcsorted, dis, b2, bufB);
    colsum_kernel<<<512, 256, 0, stream>>>(bufB, gsum);
    final_kernel<<<1, 64, 0, stream>>>(gsum, Wfc, bfc, (float*)d_out);
}

// Round 3
// 475.661 us; speedup vs baseline: 2.2288x; 1.5602x over previous
//
#include <hip/hip_runtime.h>
#include <math.h>

#define N_NODES 100000
#define N_EDGES 1250000
#define IN_DIM 6
#define HID 64
#define SCAN_BLOCK 256
#define SCAN_NBLK ((N_NODES + SCAN_BLOCK - 1) / SCAN_BLOCK)  // 391

// --- degree histogram: counts[dst]++ ---------------------------------------
__global__ void degree_hist(const int* __restrict__ dst, int* __restrict__ counts) {
    int e = blockIdx.x * blockDim.x + threadIdx.x;
    if (e < N_EDGES) atomicAdd(&counts[dst[e]], 1);
}

// --- scan phase 1: per-block sums ------------------------------------------
__global__ void block_sum_kernel(const int* __restrict__ counts, int* __restrict__ blocksums) {
    __shared__ int red[SCAN_BLOCK];
    int t = threadIdx.x;
    int i = blockIdx.x * SCAN_BLOCK + t;
    red[t] = (i < N_NODES) ? counts[i] : 0;
    __syncthreads();
    for (int off = SCAN_BLOCK / 2; off > 0; off >>= 1) {
        if (t < off) red[t] += red[t + off];
        __syncthreads();
    }
    if (t == 0) blocksums[blockIdx.x] = red[0];
}

// --- scan phase 2: single block scans the 391 block sums -> exclusive ------
__global__ __launch_bounds__(512) void scan_blocksums_kernel(const int* __restrict__ blocksums,
                                                             int* __restrict__ blockoff) {
    __shared__ int s[512];
    int t = threadIdx.x;
    s[t] = (t < SCAN_NBLK) ? blocksums[t] : 0;
    __syncthreads();
    for (int off = 1; off < 512; off <<= 1) {
        int add = (t >= off) ? s[t - off] : 0;
        __syncthreads();
        s[t] += add;
        __syncthreads();
    }
    if (t < SCAN_NBLK) blockoff[t] = (t == 0) ? 0 : s[t - 1];
}

// --- scan phase 3: per-block scan + offset -> row_ptr, cursor, dis ---------
__global__ void write_csr_kernel(const int* __restrict__ counts, const int* __restrict__ blockoff,
                                 int* __restrict__ row_ptr, int* __restrict__ cursor,
                                 float* __restrict__ dis) {
    __shared__ int s[SCAN_BLOCK];
    int t = threadIdx.x;
    int i = blockIdx.x * SCAN_BLOCK + t;
    int c = (i < N_NODES) ? counts[i] : 0;
    s[t] = c;
    __syncthreads();
    for (int off = 1; off < SCAN_BLOCK; off <<= 1) {
        int add = (t >= off) ? s[t - off] : 0;
        __syncthreads();
        s[t] += add;
        __syncthreads();
    }
    int excl = blockoff[blockIdx.x] + s[t] - c;
    if (i < N_NODES) {
        row_ptr[i] = excl;
        cursor[i]  = excl;
        dis[i] = rsqrtf((float)c + 1.0f);  // deg includes self-loop
        if (i == N_NODES - 1) row_ptr[N_NODES] = excl + c;
    }
}

// --- bucket fill: CSR-by-dst edge list (order within bucket irrelevant) ----
__global__ void bucket_kernel(const int* __restrict__ src, const int* __restrict__ dst,
                              int* __restrict__ cursor, int* __restrict__ srcsorted) {
    int e = blockIdx.x * blockDim.x + threadIdx.x;
    if (e < N_EDGES) {
        int d = dst[e];
        int pos = atomicAdd(&cursor[d], 1);
        srcsorted[pos] = src[e];
    }
}

// --- p1 = (x @ W1) * dis[n]  (6 -> 64) -------------------------------------
__global__ void gemm1_kernel(const float* __restrict__ x, const float* __restrict__ W1,
                             const float* __restrict__ dis, float* __restrict__ p1) {
    __shared__ float w[IN_DIM * HID];
    int tid = threadIdx.x;
    for (int i = tid; i < IN_DIM * HID; i += blockDim.x) w[i] = W1[i];
    __syncthreads();
    int g = blockIdx.x * blockDim.x + tid;
    int n = g >> 6, c = g & 63;
    if (n >= N_NODES) return;
    float sum = 0.f;
#pragma unroll
    for (int k = 0; k < IN_DIM; ++k) sum += x[n * IN_DIM + k] * w[k * HID + c];
    p1[n * HID + c] = sum * dis[n];
}

// --- generic aggregation: out[n] = act(dis[n]*(p[n] + sum_in p[src]) + b) --
template <bool RELU>
__global__ void agg_kernel(const float* __restrict__ p, const int* __restrict__ row_ptr,
                           const int* __restrict__ srcsorted, const float* __restrict__ dis,
                           const float* __restrict__ b, float* __restrict__ out) {
    int g = blockIdx.x * blockDim.x + threadIdx.x;
    int n = g >> 6, c = g & 63;
    if (n >= N_NODES) return;
    int beg = row_ptr[n], end = row_ptr[n + 1];
    float a0 = p[n * HID + c], a1 = 0.f, a2 = 0.f, a3 = 0.f;
    int j = beg;
    for (; j + 4 <= end; j += 4) {
        int s0 = srcsorted[j];
        int s1 = srcsorted[j + 1];
        int s2 = srcsorted[j + 2];
        int s3 = srcsorted[j + 3];
        a0 += p[s0 * HID + c];
        a1 += p[s1 * HID + c];
        a2 += p[s2 * HID + c];
        a3 += p[s3 * HID + c];
    }
    for (; j < end; ++j) a0 += p[srcsorted[j] * HID + c];
    float acc = (a0 + a1) + (a2 + a3);
    float v = dis[n] * acc + b[c];
    out[n * HID + c] = RELU ? fmaxf(v, 0.f) : v;
}

// --- p2 = (out1 @ W2) * dis[n]  (64 -> 64) ---------------------------------
__global__ void gemm2_kernel(const float* __restrict__ h, const float* __restrict__ W2,
                             const float* __restrict__ dis, float* __restrict__ p2) {
    __shared__ float w[HID * HID];
    int tid = threadIdx.x;
    for (int i = tid; i < HID * HID; i += blockDim.x) w[i] = W2[i];
    __syncthreads();
    int g = blockIdx.x * blockDim.x + tid;
    int n = g >> 6, c = g & 63;
    if (n >= N_NODES) return;
    const float* hr = h + n * HID;
    float sum = 0.f;
#pragma unroll
    for (int k = 0; k < HID; ++k) sum += hr[k] * w[k * HID + c];
    p2[n * HID + c] = sum * dis[n];
}

// --- column sum of h2 [N, 64] -> gsum[64] ----------------------------------
__global__ void colsum_kernel(const float* __restrict__ h2, float* __restrict__ gsum) {
    __shared__ float red[256];
    int tid = threadIdx.x;
    int lane = tid & 63;
    int w = tid >> 6;  // 4 waves per block
    float sum = 0.f;
    for (int n = blockIdx.x * 4 + w; n < N_NODES; n += gridDim.x * 4)
        sum += h2[n * HID + lane];
    red[tid] = sum;
    __syncthreads();
    if (tid < 64)
        atomicAdd(&gsum[tid], red[tid] + red[tid + 64] + red[tid + 128] + red[tid + 192]);
}

// --- final: sigmoid(mean(h2) @ Wfc + bfc) ----------------------------------
__global__ void final_kernel(const float* __restrict__ gsum, const float* __restrict__ Wfc,
                             const float* __restrict__ bfc, float* __restrict__ out) {
    int t = threadIdx.x;
    float v = gsum[t] * (1.0f / N_NODES) * Wfc[t];
    for (int off = 32; off > 0; off >>= 1) v += __shfl_down(v, off, 64);
    if (t == 0) out[0] = 1.0f / (1.0f + expf(-(v + bfc[0])));
}

extern "C" void kernel_launch(void* const* d_in, const int* in_sizes, int n_in,
                              void* d_out, int out_size, void* d_ws, size_t ws_size,
                              hipStream_t stream) {
    const float* x   = (const float*)d_in[0];
    const int*   ei  = (const int*)d_in[1];   // (2, E) row-major int32
    const float* W1  = (const float*)d_in[2];
    const float* b1  = (const float*)d_in[3];
    const float* W2  = (const float*)d_in[4];
    const float* b2  = (const float*)d_in[5];
    const float* Wfc = (const float*)d_in[6];
    const float* bfc = (const float*)d_in[7];
    const int* src = ei;
    const int* dst = ei + N_EDGES;

    char* ws = (char*)d_ws;
    size_t off = 0;
    auto alloc = [&](size_t bytes) {
        char* p = ws + off;
        off += (bytes + 255) & ~(size_t)255;
        return p;
    };
    float* bufA      = (float*)alloc((size_t)N_NODES * HID * 4);  // p1, then p2
    float* bufB      = (float*)alloc((size_t)N_NODES * HID * 4);  // out1, then h2
    float* dis       = (float*)alloc((size_t)N_NODES * 4);
    int*   counts    = (int*)  alloc((size_t)N_NODES * 4);
    int*   row_ptr   = (int*)  alloc((size_t)(N_NODES + 1) * 4);
    int*   cursor    = (int*)  alloc((size_t)N_NODES * 4);
    int*   srcsorted = (int*)  alloc((size_t)N_EDGES * 4);
    int*   blocksums = (int*)  alloc((size_t)SCAN_NBLK * 4);
    int*   blockoff  = (int*)  alloc((size_t)SCAN_NBLK * 4);
    float* gsum      = (float*)alloc(64 * 4);

    hipMemsetAsync(counts, 0, (size_t)N_NODES * 4, stream);
    hipMemsetAsync(gsum, 0, 64 * 4, stream);

    int eb = (N_EDGES + 255) / 256;
    int nb = (N_NODES * HID + 255) / 256;

    degree_hist<<<eb, 256, 0, stream>>>(dst, counts);
    block_sum_kernel<<<SCAN_NBLK, SCAN_BLOCK, 0, stream>>>(counts, blocksums);
    scan_blocksums_kernel<<<1, 512, 0, stream>>>(blocksums, blockoff);
    write_csr_kernel<<<SCAN_NBLK, SCAN_BLOCK, 0, stream>>>(counts, blockoff, row_ptr, cursor, dis);
    bucket_kernel<<<eb, 256, 0, stream>>>(src, dst, cursor, srcsorted);
    gemm1_kernel<<<nb, 256, 0, stream>>>(x, W1, dis, bufA);
    agg_kernel<true><<<nb, 256, 0, stream>>>(bufA, row_ptr, srcsorted, dis, b1, bufB);
    gemm2_kernel<<<nb, 256, 0, stream>>>(bufB, W2, dis, bufA);
    agg_kernel<false><<<nb, 256, 0, stream>>>(bufA, row_ptr, srcsorted, dis, b2, bufB);
    colsum_kernel<<<512, 256, 0, stream>>>(bufB, gsum);
    final_kernel<<<1, 64, 0, stream>>>(gsum, Wfc, bfc, (float*)d_out);
}

// Round 4
// 423.833 us; speedup vs baseline: 2.5013x; 1.1223x over previous
//
#include <hip/hip_runtime.h>
#include <math.h>

#define N_NODES 100000
#define N_EDGES 1250000
#define IN_DIM 6
#define HID 64
#define SCAN_BLOCK 256
#define SCAN_NBLK ((N_NODES + SCAN_BLOCK - 1) / SCAN_BLOCK)  // 391

// --- degree histogram: counts[dst]++, 4 edges/thread for MLP ---------------
__global__ void degree_hist(const int* __restrict__ dst, int* __restrict__ counts) {
    int e = (blockIdx.x * blockDim.x + threadIdx.x) * 4;
    if (e >= N_EDGES) return;
    int4 d = *(const int4*)&dst[e];
    atomicAdd(&counts[d.x], 1);
    atomicAdd(&counts[d.y], 1);
    atomicAdd(&counts[d.z], 1);
    atomicAdd(&counts[d.w], 1);
}

// --- scan phase 1: per-block sums ------------------------------------------
__global__ void block_sum_kernel(const int* __restrict__ counts, int* __restrict__ blocksums) {
    __shared__ int red[SCAN_BLOCK];
    int t = threadIdx.x;
    int i = blockIdx.x * SCAN_BLOCK + t;
    red[t] = (i < N_NODES) ? counts[i] : 0;
    __syncthreads();
    for (int off = SCAN_BLOCK / 2; off > 0; off >>= 1) {
        if (t < off) red[t] += red[t + off];
        __syncthreads();
    }
    if (t == 0) blocksums[blockIdx.x] = red[0];
}

// --- scan phase 2: single block scans the 391 block sums -> exclusive ------
__global__ __launch_bounds__(512) void scan_blocksums_kernel(const int* __restrict__ blocksums,
                                                             int* __restrict__ blockoff) {
    __shared__ int s[512];
    int t = threadIdx.x;
    s[t] = (t < SCAN_NBLK) ? blocksums[t] : 0;
    __syncthreads();
    for (int off = 1; off < 512; off <<= 1) {
        int add = (t >= off) ? s[t - off] : 0;
        __syncthreads();
        s[t] += add;
        __syncthreads();
    }
    if (t < SCAN_NBLK) blockoff[t] = (t == 0) ? 0 : s[t - 1];
}

// --- scan phase 3: per-block scan + offset -> row_ptr, cursor, dis ---------
__global__ void write_csr_kernel(const int* __restrict__ counts, const int* __restrict__ blockoff,
                                 int* __restrict__ row_ptr, int* __restrict__ cursor,
                                 float* __restrict__ dis) {
    __shared__ int s[SCAN_BLOCK];
    int t = threadIdx.x;
    int i = blockIdx.x * SCAN_BLOCK + t;
    int c = (i < N_NODES) ? counts[i] : 0;
    s[t] = c;
    __syncthreads();
    for (int off = 1; off < SCAN_BLOCK; off <<= 1) {
        int add = (t >= off) ? s[t - off] : 0;
        __syncthreads();
        s[t] += add;
        __syncthreads();
    }
    int excl = blockoff[blockIdx.x] + s[t] - c;
    if (i < N_NODES) {
        row_ptr[i] = excl;
        cursor[i]  = excl;
        dis[i] = rsqrtf((float)c + 1.0f);  // deg includes self-loop
        if (i == N_NODES - 1) row_ptr[N_NODES] = excl + c;
    }
}

// --- bucket fill: 4 edges/thread, 4 independent atomic+store chains --------
__global__ void bucket_kernel(const int* __restrict__ src, const int* __restrict__ dst,
                              int* __restrict__ cursor, int* __restrict__ srcsorted) {
    int e = (blockIdx.x * blockDim.x + threadIdx.x) * 4;
    if (e >= N_EDGES) return;
    int4 d = *(const int4*)&dst[e];
    int4 s = *(const int4*)&src[e];
    int p0 = atomicAdd(&cursor[d.x], 1);
    int p1 = atomicAdd(&cursor[d.y], 1);
    int p2 = atomicAdd(&cursor[d.z], 1);
    int p3 = atomicAdd(&cursor[d.w], 1);
    srcsorted[p0] = s.x;
    srcsorted[p1] = s.y;
    srcsorted[p2] = s.z;
    srcsorted[p3] = s.w;
}

// --- p1 = (x @ W1) * dis[n]  (6 -> 64) -------------------------------------
__global__ void gemm1_kernel(const float* __restrict__ x, const float* __restrict__ W1,
                             const float* __restrict__ dis, float* __restrict__ p1) {
    __shared__ float w[IN_DIM * HID];
    int tid = threadIdx.x;
    for (int i = tid; i < IN_DIM * HID; i += blockDim.x) w[i] = W1[i];
    __syncthreads();
    int g = blockIdx.x * blockDim.x + tid;
    int n = g >> 6, c = g & 63;
    if (n >= N_NODES) return;
    float sum = 0.f;
#pragma unroll
    for (int k = 0; k < IN_DIM; ++k) sum += x[n * IN_DIM + k] * w[k * HID + c];
    p1[n * HID + c] = sum * dis[n];
}

// --- generic aggregation: out[n] = act(dis[n]*(p[n] + sum_in p[src]) + b) --
template <bool RELU>
__global__ void agg_kernel(const float* __restrict__ p, const int* __restrict__ row_ptr,
                           const int* __restrict__ srcsorted, const float* __restrict__ dis,
                           const float* __restrict__ b, float* __restrict__ out) {
    int g = blockIdx.x * blockDim.x + threadIdx.x;
    int n = g >> 6, c = g & 63;
    if (n >= N_NODES) return;
    int beg = row_ptr[n], end = row_ptr[n + 1];
    float a0 = p[n * HID + c], a1 = 0.f, a2 = 0.f, a3 = 0.f;
    int j = beg;
    for (; j + 4 <= end; j += 4) {
        int s0 = srcsorted[j];
        int s1 = srcsorted[j + 1];
        int s2 = srcsorted[j + 2];
        int s3 = srcsorted[j + 3];
        a0 += p[s0 * HID + c];
        a1 += p[s1 * HID + c];
        a2 += p[s2 * HID + c];
        a3 += p[s3 * HID + c];
    }
    for (; j < end; ++j) a0 += p[srcsorted[j] * HID + c];
    float acc = (a0 + a1) + (a2 + a3);
    float v = dis[n] * acc + b[c];
    out[n * HID + c] = RELU ? fmaxf(v, 0.f) : v;
}

// --- p2 = (out1 @ W2) * dis[n]  (64 -> 64), LDS-tiled block GEMM -----------
// 64 nodes/block; each thread computes a 4-node x 4-channel micro-tile.
#define G2_NODES 64
__global__ __launch_bounds__(256) void gemm2_kernel(const float* __restrict__ h,
                                                    const float* __restrict__ W2,
                                                    const float* __restrict__ dis,
                                                    float* __restrict__ p2) {
    __shared__ float w[HID * HID];            // [k][c]
    __shared__ float ht[G2_NODES][HID + 1];   // [node][k], +1 pad vs bank conflicts
    int tid = threadIdx.x;
    for (int i = tid * 4; i < HID * HID; i += 256 * 4)
        *(float4*)&w[i] = *(const float4*)&W2[i];
    int n0 = blockIdx.x * G2_NODES;
    for (int i = tid; i < G2_NODES * HID / 4; i += 256) {
        int r = (i * 4) >> 6;
        int cc = (i * 4) & 63;
        float4 v = make_float4(0.f, 0.f, 0.f, 0.f);
        if (n0 + r < N_NODES) v = *(const float4*)&h[(size_t)(n0 + r) * HID + cc];
        ht[r][cc] = v.x; ht[r][cc + 1] = v.y; ht[r][cc + 2] = v.z; ht[r][cc + 3] = v.w;
    }
    __syncthreads();
    int c4 = (tid & 15) * 4;      // channel group
    int nb = (tid >> 4) * 4;      // node group
    float acc[4][4];
#pragma unroll
    for (int i = 0; i < 4; ++i)
#pragma unroll
        for (int j = 0; j < 4; ++j) acc[i][j] = 0.f;
#pragma unroll 8
    for (int k = 0; k < HID; ++k) {
        float4 wv = *(float4*)&w[k * HID + c4];
        float h0 = ht[nb + 0][k];
        float h1 = ht[nb + 1][k];
        float h2 = ht[nb + 2][k];
        float h3 = ht[nb + 3][k];
        acc[0][0] += h0 * wv.x; acc[0][1] += h0 * wv.y; acc[0][2] += h0 * wv.z; acc[0][3] += h0 * wv.w;
        acc[1][0] += h1 * wv.x; acc[1][1] += h1 * wv.y; acc[1][2] += h1 * wv.z; acc[1][3] += h1 * wv.w;
        acc[2][0] += h2 * wv.x; acc[2][1] += h2 * wv.y; acc[2][2] += h2 * wv.z; acc[2][3] += h2 * wv.w;
        acc[3][0] += h3 * wv.x; acc[3][1] += h3 * wv.y; acc[3][2] += h3 * wv.z; acc[3][3] += h3 * wv.w;
    }
#pragma unroll
    for (int i = 0; i < 4; ++i) {
        int n = n0 + nb + i;
        if (n < N_NODES) {
            float ds = dis[n];
            float4 o = make_float4(acc[i][0] * ds, acc[i][1] * ds, acc[i][2] * ds, acc[i][3] * ds);
            *(float4*)&p2[(size_t)n * HID + c4] = o;
        }
    }
}

// --- column sum of h2 [N, 64] -> gsum[64] ----------------------------------
__global__ void colsum_kernel(const float* __restrict__ h2, float* __restrict__ gsum) {
    __shared__ float red[256];
    int tid = threadIdx.x;
    int lane = tid & 63;
    int w = tid >> 6;  // 4 waves per block
    float sum = 0.f;
    for (int n = blockIdx.x * 4 + w; n < N_NODES; n += gridDim.x * 4)
        sum += h2[n * HID + lane];
    red[tid] = sum;
    __syncthreads();
    if (tid < 64)
        atomicAdd(&gsum[tid], red[tid] + red[tid + 64] + red[tid + 128] + red[tid + 192]);
}

// --- final: sigmoid(mean(h2) @ Wfc + bfc) ----------------------------------
__global__ void final_kernel(const float* __restrict__ gsum, const float* __restrict__ Wfc,
                             const float* __restrict__ bfc, float* __restrict__ out) {
    int t = threadIdx.x;
    float v = gsum[t] * (1.0f / N_NODES) * Wfc[t];
    for (int off = 32; off > 0; off >>= 1) v += __shfl_down(v, off, 64);
    if (t == 0) out[0] = 1.0f / (1.0f + expf(-(v + bfc[0])));
}

extern "C" void kernel_launch(void* const* d_in, const int* in_sizes, int n_in,
                              void* d_out, int out_size, void* d_ws, size_t ws_size,
                              hipStream_t stream) {
    const float* x   = (const float*)d_in[0];
    const int*   ei  = (const int*)d_in[1];   // (2, E) row-major int32
    const float* W1  = (const float*)d_in[2];
    const float* b1  = (const float*)d_in[3];
    const float* W2  = (const float*)d_in[4];
    const float* b2  = (const float*)d_in[5];
    const float* Wfc = (const float*)d_in[6];
    const float* bfc = (const float*)d_in[7];
    const int* src = ei;
    const int* dst = ei + N_EDGES;

    char* ws = (char*)d_ws;
    size_t off = 0;
    auto alloc = [&](size_t bytes) {
        char* p = ws + off;
        off += (bytes + 255) & ~(size_t)255;
        return p;
    };
    float* bufA      = (float*)alloc((size_t)N_NODES * HID * 4);  // p1, then p2
    float* bufB      = (float*)alloc((size_t)N_NODES * HID * 4);  // out1, then h2
    float* dis       = (float*)alloc((size_t)N_NODES * 4);
    int*   counts    = (int*)  alloc((size_t)N_NODES * 4);
    int*   row_ptr   = (int*)  alloc((size_t)(N_NODES + 1) * 4);
    int*   cursor    = (int*)  alloc((size_t)N_NODES * 4);
    int*   srcsorted = (int*)  alloc((size_t)N_EDGES * 4);
    int*   blocksums = (int*)  alloc((size_t)SCAN_NBLK * 4);
    int*   blockoff  = (int*)  alloc((size_t)SCAN_NBLK * 4);
    float* gsum      = (float*)alloc(64 * 4);

    hipMemsetAsync(counts, 0, (size_t)N_NODES * 4, stream);
    hipMemsetAsync(gsum, 0, 64 * 4, stream);

    int eb4 = (N_EDGES / 4 + 255) / 256;            // 4 edges/thread kernels
    int nb = (N_NODES * HID + 255) / 256;
    int g2b = (N_NODES + G2_NODES - 1) / G2_NODES;  // 1563

    degree_hist<<<eb4, 256, 0, stream>>>(dst, counts);
    block_sum_kernel<<<SCAN_NBLK, SCAN_BLOCK, 0, stream>>>(counts, blocksums);
    scan_blocksums_kernel<<<1, 512, 0, stream>>>(blocksums, blockoff);
    write_csr_kernel<<<SCAN_NBLK, SCAN_BLOCK, 0, stream>>>(counts, blockoff, row_ptr, cursor, dis);
    bucket_kernel<<<eb4, 256, 0, stream>>>(src, dst, cursor, srcsorted);
    gemm1_kernel<<<nb, 256, 0, stream>>>(x, W1, dis, bufA);
    agg_kernel<true><<<nb, 256, 0, stream>>>(bufA, row_ptr, srcsorted, dis, b1, bufB);
    gemm2_kernel<<<g2b, 256, 0, stream>>>(bufB, W2, dis, bufA);
    agg_kernel<false><<<nb, 256, 0, stream>>>(bufA, row_ptr, srcsorted, dis, b2, bufB);
    colsum_kernel<<<512, 256, 0, stream>>>(bufB, gsum);
    final_kernel<<<1, 64, 0, stream>>>(gsum, Wfc, bfc, (float*)d_out);
}